// Round 2
// baseline (26565.823 us; speedup 1.0000x reference)
//
#include <hip/hip_runtime.h>
#include <math.h>
#include <cstddef>

#define N_PTS 131072
#define SDIM  512
#define D1    513

static constexpr int NITER = 100;
static constexpr int BLK   = 512;            // 8 waves / block
static constexpr int GRID  = 1024;           // 4 blocks / CU (LDS 33KB x4 = 133KB fits 160KB)
static constexpr int WPB   = BLK / 64;       // waves per block
static constexpr int TW    = GRID * WPB;     // 8192 waves
static constexpr int RPW   = N_PTS / TW;     // 16 rows per wave
static constexpr int NB    = 16;             // atomic banks

struct Ws {
  double acc[NB][514];    // [.][0..511] spatial sums, [.][512] time sum, [.][513] cc sum
  unsigned int counter;
  unsigned int pad;
  float mean[513];        // [0] = time coordinate
};

template<bool INIT>
__device__ void finalize_wave(Ws* ws, int l)
{
  // sum the banks for this lane's columns
  double sv[9];
  #pragma unroll
  for (int q = 0; q < 9; ++q) {
    int c = q * 64 + l;
    sv[q] = 0.0;
    if (c < D1) {
      int idx = (c == 0) ? 512 : (c - 1);
      double s = 0.0;
      #pragma unroll
      for (int b = 0; b < NB; ++b) s += ws->acc[b][idx];
      sv[q] = s;
    }
  }
  double cc = 0.0;
  if constexpr (!INIT) {
    #pragma unroll
    for (int b = 0; b < NB; ++b) cc += ws->acc[b][513];
  }

  if constexpr (INIT) {
    double r[9]; double s2 = 0.0;
    #pragma unroll
    for (int q = 0; q < 9; ++q) {
      int c = q * 64 + l;
      r[q] = 0.0;
      if (c < D1) { r[q] = sv[q] / (double)N_PTS; s2 += r[q] * r[q]; }
    }
    #pragma unroll
    for (int m = 1; m < 64; m <<= 1) s2 += __shfl_xor(s2, m);
    double r0 = __shfl(r[0], 0);
    double inv = 1.0 / sqrt(fabs(s2 - 2.0 * r0 * r0));
    #pragma unroll
    for (int q = 0; q < 9; ++q) {
      int c = q * 64 + l;
      if (c < D1) ws->mean[c] = (float)(r[q] * inv);
    }
  } else {
    double mv[9], yv[9]; double sy = 0.0;
    #pragma unroll
    for (int q = 0; q < 9; ++q) {
      int c = q * 64 + l;
      mv[q] = 0.0; yv[q] = 0.0;
      if (c < D1) {
        double m = (double)ws->mean[c];
        double y = 0.02 * (sv[q] - cc * m) / (double)N_PTS;  // y = -R*g, R=0.01
        mv[q] = m; yv[q] = y;
        sy += y * y;
      }
    }
    #pragma unroll
    for (int m = 1; m < 64; m <<= 1) sy += __shfl_xor(sy, m);
    double y0 = __shfl(yv[0], 0);
    double n = sqrt(fabs(sy - 2.0 * y0 * y0));
    n = fmax(n, 1e-5);
    double ch = cosh(n);
    double sn = (n < 1e-4) ? (1.0 + n * n / 6.0) : (sinh(n) / n);
    double nm[9]; double s2 = 0.0;
    #pragma unroll
    for (int q = 0; q < 9; ++q) {
      int c = q * 64 + l;
      nm[q] = 0.0;
      if (c < D1) { nm[q] = ch * mv[q] + sn * yv[q]; s2 += nm[q] * nm[q]; }
    }
    #pragma unroll
    for (int m = 1; m < 64; m <<= 1) s2 += __shfl_xor(s2, m);
    double m0n = __shfl(nm[0], 0);
    double inv = 1.0 / sqrt(fabs(s2 - 2.0 * m0n * m0n));
    #pragma unroll
    for (int q = 0; q < 9; ++q) {
      int c = q * 64 + l;
      if (c < D1) ws->mean[c] = (float)(nm[q] * inv);
    }
  }
}

template<bool INIT>
__global__ __launch_bounds__(BLK, 4)
void reduce_kernel(const float* __restrict__ data, Ws* __restrict__ ws, int rev)
{
  const int lane = threadIdx.x & 63;
  const int wid  = threadIdx.x >> 6;
  const int gw   = blockIdx.x * WPB + wid;

  float m0 = 0.f;
  float mk0=0.f, mk1=0.f, mk2=0.f, mk3=0.f, mk4=0.f, mk5=0.f, mk6=0.f, mk7=0.f;
  if constexpr (!INIT) {
    m0 = ws->mean[0];
    const float* msp = ws->mean + 1;
    mk0 = msp[lane*4 + 0]; mk1 = msp[lane*4 + 1];
    mk2 = msp[lane*4 + 2]; mk3 = msp[lane*4 + 3];
    mk4 = msp[256 + lane*4 + 0]; mk5 = msp[256 + lane*4 + 1];
    mk6 = msp[256 + lane*4 + 2]; mk7 = msp[256 + lane*4 + 3];
  }

  double a0=0,a1=0,a2=0,a3=0,a4=0,a5=0,a6=0,a7=0;
  double acc_t = 0.0, acc_cc = 0.0;

  // software pipeline: next row's loads in flight across current row's chain
  {
    int rr0  = gw * RPW;
    int row0 = rev ? (N_PTS - 1 - rr0) : rr0;
    const float4* p4 = (const float4*)(data + (size_t)row0 * SDIM);
    float4 va = p4[lane];
    float4 vb = p4[64 + lane];

    for (int k = 0; k < RPW; ++k) {
      float4 na, nb;
      if (k + 1 < RPW) {
        int rr  = gw * RPW + k + 1;
        int row = rev ? (N_PTS - 1 - rr) : rr;
        const float4* q4 = (const float4*)(data + (size_t)row * SDIM);
        na = q4[lane]; nb = q4[64 + lane];
      } else { na = va; nb = vb; }

      float sq = va.x * va.x;
      sq = fmaf(va.y, va.y, sq);
      sq = fmaf(va.z, va.z, sq);
      sq = fmaf(va.w, va.w, sq);
      sq = fmaf(vb.x, vb.x, sq);
      sq = fmaf(vb.y, vb.y, sq);
      sq = fmaf(vb.z, vb.z, sq);
      sq = fmaf(vb.w, vb.w, sq);

      float dot = 0.f;
      if constexpr (!INIT) {
        dot = va.x * mk0;
        dot = fmaf(va.y, mk1, dot);
        dot = fmaf(va.z, mk2, dot);
        dot = fmaf(va.w, mk3, dot);
        dot = fmaf(vb.x, mk4, dot);
        dot = fmaf(vb.y, mk5, dot);
        dot = fmaf(vb.z, mk6, dot);
        dot = fmaf(vb.w, mk7, dot);
      }

      #pragma unroll
      for (int m = 1; m < 64; m <<= 1) {
        sq += __shfl_xor(sq, m);
        if constexpr (!INIT) dot += __shfl_xor(dot, m);
      }

      float t = sqrtf(1.0f + sq);
      float c1;
      if constexpr (INIT) {
        c1 = 1.0f;
      } else {
        float a = m0 * t - dot;            // -mdot(mean, p_i)
        float x = fmaxf(a, 1.0f + 1e-5f);
        float s = sqrtf(x * x - 1.0f);     // sinh(d)
        float d = logf(x + s);             // arccosh(x)
        c1 = d / s;                        // d / sinh(d)
        acc_cc += (double)c1 * (double)x;  // c1 * cosh(d)
      }
      acc_t += (double)c1 * (double)t;

      double c1d = (double)c1;
      a0 = fma(c1d, (double)va.x, a0);
      a1 = fma(c1d, (double)va.y, a1);
      a2 = fma(c1d, (double)va.z, a2);
      a3 = fma(c1d, (double)va.w, a3);
      a4 = fma(c1d, (double)vb.x, a4);
      a5 = fma(c1d, (double)vb.y, a5);
      a6 = fma(c1d, (double)vb.z, a6);
      a7 = fma(c1d, (double)vb.w, a7);

      va = na; vb = nb;
    }
  }

  // block-level reduction across waves in LDS
  __shared__ double s_red[WPB][514];
  {
    int b = lane * 4;
    s_red[wid][b + 0] = a0; s_red[wid][b + 1] = a1;
    s_red[wid][b + 2] = a2; s_red[wid][b + 3] = a3;
    s_red[wid][256 + b + 0] = a4; s_red[wid][256 + b + 1] = a5;
    s_red[wid][256 + b + 2] = a6; s_red[wid][256 + b + 3] = a7;
    if (lane == 0) { s_red[wid][512] = acc_t; s_red[wid][513] = acc_cc; }
  }
  __syncthreads();

  // banked, column-staggered atomics: spread hot lines by 16x and
  // decorrelate the per-block burst order
  {
    double* bank = ws->acc[blockIdx.x & (NB - 1)];
    int rot = (blockIdx.x * 131) & 511;
    for (int j = threadIdx.x; j < 514; j += BLK) {
      int c = (j < 512) ? ((j + rot) & 511) : j;
      double s = 0.0;
      #pragma unroll
      for (int w = 0; w < WPB; ++w) s += s_red[w][c];
      atomicAdd(&bank[c], s);
    }
  }
  __threadfence();
  __syncthreads();

  __shared__ unsigned int s_ticket;
  if (threadIdx.x == 0) s_ticket = atomicAdd(&ws->counter, 1u);
  __syncthreads();

  if (s_ticket == (unsigned)(GRID - 1)) {
    __threadfence();   // acquire: make all blocks' atomics visible
    if (threadIdx.x < 64) finalize_wave<INIT>(ws, threadIdx.x);
    __syncthreads();   // finalize's acc reads complete before zeroing
    for (int i = threadIdx.x; i < NB * 514; i += BLK) ((double*)ws->acc)[i] = 0.0;
    if (threadIdx.x == 0) ws->counter = 0u;
  }
}

__global__ void write_out_kernel(const float* __restrict__ mean, float* __restrict__ out)
{
  int i = threadIdx.x;
  if (i < SDIM) out[i] = mean[1 + i];
}

extern "C" void kernel_launch(void* const* d_in, const int* in_sizes, int n_in,
                              void* d_out, int out_size, void* d_ws, size_t ws_size,
                              hipStream_t stream)
{
  (void)in_sizes; (void)n_in; (void)out_size; (void)ws_size;
  const float* data = (const float*)d_in[0];
  Ws* ws = (Ws*)d_ws;

  // zero accumulators + ticket counter (mean is fully written by the init pass)
  hipMemsetAsync(d_ws, 0, offsetof(Ws, mean), stream);

  // init pass: mean = normalize(mean over N of projected)
  reduce_kernel<true><<<dim3(GRID), dim3(BLK), 0, stream>>>(data, ws, 0);

  // 100 fixed-point iterations; alternate sweep direction for L3 reuse
  for (int it = 0; it < NITER; ++it) {
    reduce_kernel<false><<<dim3(GRID), dim3(BLK), 0, stream>>>(data, ws, (it & 1) ^ 1);
  }

  float* meanp = (float*)((char*)d_ws + offsetof(Ws, mean));
  write_out_kernel<<<dim3(1), dim3(512), 0, stream>>>(meanp, (float*)d_out);
}

// Round 3
// 21466.257 us; speedup vs baseline: 1.2376x; 1.2376x over previous
//
#include <hip/hip_runtime.h>
#include <math.h>
#include <cstddef>

#define N_PTS 131072
#define SDIM  512
#define D1    513

static constexpr int NITER = 100;
static constexpr int BLK   = 512;            // 8 waves / block
static constexpr int GRID  = 512;            // 2 blocks / CU -> all blocks resident (deadlock-safe spin)
static constexpr int WPB   = BLK / 64;       // 8 waves per block
static constexpr int TW    = GRID * WPB;     // 4096 waves
static constexpr int RPW   = N_PTS / TW;     // 32 rows per wave
static constexpr int NR    = 64;             // reducer blocks (last NR tickets)

struct Ws {
  unsigned int t1, t2;
  unsigned int pad[2];
  double colsum[514];          // [0..511] spatial, [512] t-sum, [513] cc-sum
  double part[514][GRID];      // column-major per-block partials: part[c][b]
  float mean[513];             // [0] = time coordinate
};

template<bool INIT>
__device__ void finalize_wave(Ws* ws, int l)
{
  double sv[9];
  #pragma unroll
  for (int q = 0; q < 9; ++q) {
    int c = q * 64 + l;
    sv[q] = 0.0;
    if (c < D1) sv[q] = ws->colsum[(c == 0) ? 512 : (c - 1)];
  }

  if constexpr (INIT) {
    double r[9]; double s2 = 0.0;
    #pragma unroll
    for (int q = 0; q < 9; ++q) {
      int c = q * 64 + l;
      r[q] = 0.0;
      if (c < D1) { r[q] = sv[q] / (double)N_PTS; s2 += r[q] * r[q]; }
    }
    #pragma unroll
    for (int m = 1; m < 64; m <<= 1) s2 += __shfl_xor(s2, m);
    double r0 = __shfl(r[0], 0);
    double inv = 1.0 / sqrt(fabs(s2 - 2.0 * r0 * r0));
    #pragma unroll
    for (int q = 0; q < 9; ++q) {
      int c = q * 64 + l;
      if (c < D1) ws->mean[c] = (float)(r[q] * inv);
    }
  } else {
    double cc = ws->colsum[513];
    double mv[9], yv[9]; double sy = 0.0;
    #pragma unroll
    for (int q = 0; q < 9; ++q) {
      int c = q * 64 + l;
      mv[q] = 0.0; yv[q] = 0.0;
      if (c < D1) {
        double m = (double)ws->mean[c];
        double y = 0.02 * (sv[q] - cc * m) / (double)N_PTS;  // y = -R*g, R=0.01
        mv[q] = m; yv[q] = y;
        sy += y * y;
      }
    }
    #pragma unroll
    for (int m = 1; m < 64; m <<= 1) sy += __shfl_xor(sy, m);
    double y0 = __shfl(yv[0], 0);
    double n = sqrt(fabs(sy - 2.0 * y0 * y0));
    n = fmax(n, 1e-5);
    double ch = cosh(n);
    double sn = (n < 1e-4) ? (1.0 + n * n / 6.0) : (sinh(n) / n);
    double nm[9]; double s2 = 0.0;
    #pragma unroll
    for (int q = 0; q < 9; ++q) {
      int c = q * 64 + l;
      nm[q] = 0.0;
      if (c < D1) { nm[q] = ch * mv[q] + sn * yv[q]; s2 += nm[q] * nm[q]; }
    }
    #pragma unroll
    for (int m = 1; m < 64; m <<= 1) s2 += __shfl_xor(s2, m);
    double m0n = __shfl(nm[0], 0);
    double inv = 1.0 / sqrt(fabs(s2 - 2.0 * m0n * m0n));
    #pragma unroll
    for (int q = 0; q < 9; ++q) {
      int c = q * 64 + l;
      if (c < D1) ws->mean[c] = (float)(nm[q] * inv);
    }
  }
}

template<bool INIT>
__global__ __launch_bounds__(BLK, 4)
void reduce_kernel(const float* __restrict__ data, Ws* __restrict__ ws, int rev)
{
  const int lane = threadIdx.x & 63;
  const int wid  = threadIdx.x >> 6;
  const int gw   = blockIdx.x * WPB + wid;

  float m0 = 0.f;
  float mk0=0.f, mk1=0.f, mk2=0.f, mk3=0.f, mk4=0.f, mk5=0.f, mk6=0.f, mk7=0.f;
  if constexpr (!INIT) {
    m0 = ws->mean[0];
    const float* msp = ws->mean + 1;
    mk0 = msp[lane*4 + 0]; mk1 = msp[lane*4 + 1];
    mk2 = msp[lane*4 + 2]; mk3 = msp[lane*4 + 3];
    mk4 = msp[256 + lane*4 + 0]; mk5 = msp[256 + lane*4 + 1];
    mk6 = msp[256 + lane*4 + 2]; mk7 = msp[256 + lane*4 + 3];
  }

  double a0=0,a1=0,a2=0,a3=0,a4=0,a5=0,a6=0,a7=0;
  double acc_t = 0.0, acc_cc = 0.0;

  // software pipeline: next row's loads in flight across current row's chain
  {
    int rr0  = gw * RPW;
    int row0 = rev ? (N_PTS - 1 - rr0) : rr0;
    const float4* p4 = (const float4*)(data + (size_t)row0 * SDIM);
    float4 va = p4[lane];
    float4 vb = p4[64 + lane];

    for (int k = 0; k < RPW; ++k) {
      float4 na, nb;
      if (k + 1 < RPW) {
        int rr  = gw * RPW + k + 1;
        int row = rev ? (N_PTS - 1 - rr) : rr;
        const float4* q4 = (const float4*)(data + (size_t)row * SDIM);
        na = q4[lane]; nb = q4[64 + lane];
      } else { na = va; nb = vb; }

      float sq = va.x * va.x;
      sq = fmaf(va.y, va.y, sq);
      sq = fmaf(va.z, va.z, sq);
      sq = fmaf(va.w, va.w, sq);
      sq = fmaf(vb.x, vb.x, sq);
      sq = fmaf(vb.y, vb.y, sq);
      sq = fmaf(vb.z, vb.z, sq);
      sq = fmaf(vb.w, vb.w, sq);

      float dot = 0.f;
      if constexpr (!INIT) {
        dot = va.x * mk0;
        dot = fmaf(va.y, mk1, dot);
        dot = fmaf(va.z, mk2, dot);
        dot = fmaf(va.w, mk3, dot);
        dot = fmaf(vb.x, mk4, dot);
        dot = fmaf(vb.y, mk5, dot);
        dot = fmaf(vb.z, mk6, dot);
        dot = fmaf(vb.w, mk7, dot);
      }

      #pragma unroll
      for (int m = 1; m < 64; m <<= 1) {
        sq += __shfl_xor(sq, m);
        if constexpr (!INIT) dot += __shfl_xor(dot, m);
      }

      float t = sqrtf(1.0f + sq);
      float c1;
      if constexpr (INIT) {
        c1 = 1.0f;
      } else {
        float a = m0 * t - dot;            // -mdot(mean, p_i)
        float x = fmaxf(a, 1.0f + 1e-5f);
        float s = sqrtf(x * x - 1.0f);     // sinh(d)
        float d = logf(x + s);             // arccosh(x)
        c1 = d / s;                        // d / sinh(d)
        acc_cc += (double)c1 * (double)x;  // c1 * cosh(d)
      }
      acc_t += (double)c1 * (double)t;

      double c1d = (double)c1;
      a0 = fma(c1d, (double)va.x, a0);
      a1 = fma(c1d, (double)va.y, a1);
      a2 = fma(c1d, (double)va.z, a2);
      a3 = fma(c1d, (double)va.w, a3);
      a4 = fma(c1d, (double)vb.x, a4);
      a5 = fma(c1d, (double)vb.y, a5);
      a6 = fma(c1d, (double)vb.z, a6);
      a7 = fma(c1d, (double)vb.w, a7);

      va = na; vb = nb;
    }
  }

  // block-level reduction across waves in LDS
  __shared__ double s_red[WPB][514];
  {
    int b = lane * 4;
    s_red[wid][b + 0] = a0; s_red[wid][b + 1] = a1;
    s_red[wid][b + 2] = a2; s_red[wid][b + 3] = a3;
    s_red[wid][256 + b + 0] = a4; s_red[wid][256 + b + 1] = a5;
    s_red[wid][256 + b + 2] = a6; s_red[wid][256 + b + 3] = a7;
    if (lane == 0) { s_red[wid][512] = acc_t; s_red[wid][513] = acc_cc; }
  }
  __syncthreads();

  // plain-store per-block partials, column-major (NO data atomics)
  for (int c = threadIdx.x; c < 514; c += BLK) {
    double s = 0.0;
    #pragma unroll
    for (int w = 0; w < WPB; ++w) s += s_red[w][c];
    ws->part[c][blockIdx.x] = s;
  }
  __threadfence();
  __syncthreads();

  __shared__ unsigned int s_t;
  if (threadIdx.x == 0) s_t = atomicAdd(&ws->t1, 1u);
  __syncthreads();
  const unsigned int t = s_t;
  if (t < (unsigned)(GRID - NR)) return;   // not a reducer

  // ---- reducer: wait for all blocks' partials ----
  if (threadIdx.x == 0) {
    while (__hip_atomic_load(&ws->t1, __ATOMIC_RELAXED, __HIP_MEMORY_SCOPE_AGENT)
           < (unsigned)GRID) {
      __builtin_amdgcn_s_sleep(1);
    }
  }
  __syncthreads();
  __threadfence();   // acquire

  const int r = (int)t - (GRID - NR);      // 0..NR-1
  {
    // wave w reduces column c = r + w*NR (+ tail cols 512,513 on wave 0 of r<2)
    for (int c = r + wid * NR; c < 514; c += NR * WPB) {
      double s = 0.0;
      #pragma unroll
      for (int k = 0; k < GRID / 64; ++k) s += ws->part[c][lane + 64 * k];
      #pragma unroll
      for (int m = 1; m < 64; m <<= 1) s += __shfl_xor(s, m);
      if (lane == 0) ws->colsum[c] = s;
    }
  }
  __threadfence();
  __syncthreads();

  __shared__ unsigned int s_u;
  if (threadIdx.x == 0) s_u = atomicAdd(&ws->t2, 1u);
  __syncthreads();
  if (s_u == (unsigned)(NR - 1)) {
    __threadfence();   // acquire: all colsum writes visible
    if (threadIdx.x < 64) finalize_wave<INIT>(ws, threadIdx.x);
    if (threadIdx.x == 0) { ws->t1 = 0u; ws->t2 = 0u; }
  }
}

__global__ void write_out_kernel(const float* __restrict__ mean, float* __restrict__ out)
{
  int i = threadIdx.x;
  if (i < SDIM) out[i] = mean[1 + i];
}

extern "C" void kernel_launch(void* const* d_in, const int* in_sizes, int n_in,
                              void* d_out, int out_size, void* d_ws, size_t ws_size,
                              hipStream_t stream)
{
  (void)in_sizes; (void)n_in; (void)out_size; (void)ws_size;
  const float* data = (const float*)d_in[0];
  Ws* ws = (Ws*)d_ws;

  // zero the two ticket counters (everything else is fully overwritten each pass)
  hipMemsetAsync(d_ws, 0, 16, stream);

  // init pass: mean = normalize(mean over N of projected)
  reduce_kernel<true><<<dim3(GRID), dim3(BLK), 0, stream>>>(data, ws, 0);

  // 100 fixed-point iterations; alternate sweep direction for L3 reuse
  for (int it = 0; it < NITER; ++it) {
    reduce_kernel<false><<<dim3(GRID), dim3(BLK), 0, stream>>>(data, ws, (it & 1) ^ 1);
  }

  float* meanp = (float*)((char*)d_ws + offsetof(Ws, mean));
  write_out_kernel<<<dim3(1), dim3(512), 0, stream>>>(meanp, (float*)d_out);
}

// Round 4
// 6381.590 us; speedup vs baseline: 4.1629x; 3.3638x over previous
//
#include <hip/hip_runtime.h>
#include <math.h>
#include <cstddef>

#define N_PTS 131072
#define SDIM  512
#define D1    513

static constexpr int NITER = 100;
static constexpr int BLK   = 512;            // 8 waves / block
static constexpr int GRID  = 512;            // 2 blocks / CU
static constexpr int WPB   = BLK / 64;       // 8 waves per block
static constexpr int NW    = GRID * WPB;     // 4096 waves
static constexpr int NPAIR = N_PTS / 2;      // 65536 row-pairs
static constexpr int PPW   = NPAIR / NW;     // 16 pairs per wave

struct Ws {
  double colsum[514];          // [0..511] spatial, [512] t-sum, [513] cc-sum
  double part[514][GRID];      // column-major per-block partials
  float  mean[513];            // [0] = time coordinate
};

// ---------------- streaming kernel: partials only, no cross-block sync ----------------
template<bool INIT>
__global__ __launch_bounds__(BLK, 4)
void big_kernel(const float* __restrict__ data, Ws* __restrict__ ws, int rev)
{
  const int l    = threadIdx.x & 63;
  const int sl   = l & 31;       // lane within half
  const int half = l >> 5;       // 0: even row of pair, 1: odd row
  const int wid  = threadIdx.x >> 6;
  const int gw   = blockIdx.x * WPB + wid;   // 0..NW-1

  float  m0 = 0.f;
  float4 mk0 = {0,0,0,0}, mk1 = {0,0,0,0}, mk2 = {0,0,0,0}, mk3 = {0,0,0,0};
  if constexpr (!INIT) {
    m0 = ws->mean[0];
    const float4* mp = (const float4*)(ws->mean + 1);
    mk0 = mp[0*32 + sl]; mk1 = mp[1*32 + sl];
    mk2 = mp[2*32 + sl]; mk3 = mp[3*32 + sl];
  }

  // 16 f64 accumulators per lane; lane covers cols (j*32+sl)*4 + i
  double acc[4][4] = {};
  double acc_t = 0.0, acc_cc = 0.0;

  const int p0 = gw * PPW;

  float4 c0, c1v, c2, c3, n0, n1, n2, n3;
  {
    int pr = rev ? (NPAIR - 1 - p0) : p0;
    const float4* b = (const float4*)(data + (size_t)(2 * pr + half) * SDIM);
    c0 = b[0*32 + sl]; c1v = b[1*32 + sl]; c2 = b[2*32 + sl]; c3 = b[3*32 + sl];
  }

  for (int k = 0; k < PPW; ++k) {
    const bool hasnext = (k + 1 < PPW);
    if (hasnext) {
      int p  = p0 + k + 1;
      int pr = rev ? (NPAIR - 1 - p) : p;
      const float4* b = (const float4*)(data + (size_t)(2 * pr + half) * SDIM);
      n0 = b[0*32 + sl]; n1 = b[1*32 + sl]; n2 = b[2*32 + sl]; n3 = b[3*32 + sl];
    }

    // per-lane partial sq & dot over 16 values
    float sq = c0.x * c0.x;
    sq = fmaf(c0.y, c0.y, sq); sq = fmaf(c0.z, c0.z, sq); sq = fmaf(c0.w, c0.w, sq);
    sq = fmaf(c1v.x, c1v.x, sq); sq = fmaf(c1v.y, c1v.y, sq);
    sq = fmaf(c1v.z, c1v.z, sq); sq = fmaf(c1v.w, c1v.w, sq);
    sq = fmaf(c2.x, c2.x, sq); sq = fmaf(c2.y, c2.y, sq);
    sq = fmaf(c2.z, c2.z, sq); sq = fmaf(c2.w, c2.w, sq);
    sq = fmaf(c3.x, c3.x, sq); sq = fmaf(c3.y, c3.y, sq);
    sq = fmaf(c3.z, c3.z, sq); sq = fmaf(c3.w, c3.w, sq);

    float dot = 0.f;
    if constexpr (!INIT) {
      dot = c0.x * mk0.x;
      dot = fmaf(c0.y, mk0.y, dot); dot = fmaf(c0.z, mk0.z, dot); dot = fmaf(c0.w, mk0.w, dot);
      dot = fmaf(c1v.x, mk1.x, dot); dot = fmaf(c1v.y, mk1.y, dot);
      dot = fmaf(c1v.z, mk1.z, dot); dot = fmaf(c1v.w, mk1.w, dot);
      dot = fmaf(c2.x, mk2.x, dot); dot = fmaf(c2.y, mk2.y, dot);
      dot = fmaf(c2.z, mk2.z, dot); dot = fmaf(c2.w, mk2.w, dot);
      dot = fmaf(c3.x, mk3.x, dot); dot = fmaf(c3.y, mk3.y, dot);
      dot = fmaf(c3.z, mk3.z, dot); dot = fmaf(c3.w, mk3.w, dot);
    }

    // 5-level butterfly, stays within each 32-lane half (two rows reduced at once)
    #pragma unroll
    for (int m = 1; m < 32; m <<= 1) {
      sq += __shfl_xor(sq, m);
      if constexpr (!INIT) dot += __shfl_xor(dot, m);
    }

    float t = sqrtf(1.0f + sq);
    float w;
    if constexpr (INIT) {
      w = 1.0f;
    } else {
      float a = fmaf(m0, t, -dot);       // -mdot(mean, p)
      float x = fmaxf(a, 1.0f + 1e-5f);
      float s = sqrtf(fmaf(x, x, -1.0f)); // sinh(d)
      float d = logf(x + s);              // arccosh(x)
      w = d / s;                          // d / sinh(d)
      if (sl == 0) acc_cc = fma((double)w, (double)x, acc_cc);
    }
    if (sl == 0) acc_t = fma((double)w, (double)t, acc_t);

    double wd = (double)w;
    acc[0][0] = fma(wd, (double)c0.x, acc[0][0]);
    acc[0][1] = fma(wd, (double)c0.y, acc[0][1]);
    acc[0][2] = fma(wd, (double)c0.z, acc[0][2]);
    acc[0][3] = fma(wd, (double)c0.w, acc[0][3]);
    acc[1][0] = fma(wd, (double)c1v.x, acc[1][0]);
    acc[1][1] = fma(wd, (double)c1v.y, acc[1][1]);
    acc[1][2] = fma(wd, (double)c1v.z, acc[1][2]);
    acc[1][3] = fma(wd, (double)c1v.w, acc[1][3]);
    acc[2][0] = fma(wd, (double)c2.x, acc[2][0]);
    acc[2][1] = fma(wd, (double)c2.y, acc[2][1]);
    acc[2][2] = fma(wd, (double)c2.z, acc[2][2]);
    acc[2][3] = fma(wd, (double)c2.w, acc[2][3]);
    acc[3][0] = fma(wd, (double)c3.x, acc[3][0]);
    acc[3][1] = fma(wd, (double)c3.y, acc[3][1]);
    acc[3][2] = fma(wd, (double)c3.z, acc[3][2]);
    acc[3][3] = fma(wd, (double)c3.w, acc[3][3]);

    if (hasnext) { c0 = n0; c1v = n1; c2 = n2; c3 = n3; }
  }

  // merge the two halves (same column sets): xor-32 shuffle on f64 accs
  #pragma unroll
  for (int j = 0; j < 4; ++j) {
    #pragma unroll
    for (int i = 0; i < 4; ++i) acc[j][i] += __shfl_xor(acc[j][i], 32);
  }
  acc_t  += __shfl_xor(acc_t, 32);
  acc_cc += __shfl_xor(acc_cc, 32);

  __shared__ double s_red[WPB][514];
  if (half == 0) {
    #pragma unroll
    for (int j = 0; j < 4; ++j) {
      #pragma unroll
      for (int i = 0; i < 4; ++i) s_red[wid][(j*32 + sl)*4 + i] = acc[j][i];
    }
  }
  if (l == 0) { s_red[wid][512] = acc_t; s_red[wid][513] = acc_cc; }
  __syncthreads();

  for (int c = threadIdx.x; c < 514; c += BLK) {
    double s = 0.0;
    #pragma unroll
    for (int w2 = 0; w2 < WPB; ++w2) s += s_red[w2][c];
    ws->part[c][blockIdx.x] = s;
  }
}

// ---------------- per-column reduce: one wave per column ----------------
__global__ __launch_bounds__(64)
void colreduce_kernel(Ws* __restrict__ ws)
{
  const int c = blockIdx.x;       // 0..513
  const int l = threadIdx.x;
  const double* col = ws->part[c];
  double s = 0.0;
  #pragma unroll
  for (int k = 0; k < GRID / 64; ++k) s += col[l + 64 * k];
  #pragma unroll
  for (int m = 1; m < 64; m <<= 1) s += __shfl_xor(s, m);
  if (l == 0) ws->colsum[c] = s;
}

// ---------------- finalize: one wave does the exp-map update ----------------
template<bool INIT>
__global__ __launch_bounds__(64)
void finalize_kernel(Ws* __restrict__ ws)
{
  const int l = threadIdx.x;
  double sv[9];
  #pragma unroll
  for (int q = 0; q < 9; ++q) {
    int c = q * 64 + l;
    sv[q] = 0.0;
    if (c < D1) sv[q] = ws->colsum[(c == 0) ? 512 : (c - 1)];
  }

  if constexpr (INIT) {
    double r[9]; double s2 = 0.0;
    #pragma unroll
    for (int q = 0; q < 9; ++q) {
      int c = q * 64 + l;
      r[q] = 0.0;
      if (c < D1) { r[q] = sv[q] / (double)N_PTS; s2 += r[q] * r[q]; }
    }
    #pragma unroll
    for (int m = 1; m < 64; m <<= 1) s2 += __shfl_xor(s2, m);
    double r0 = __shfl(r[0], 0);
    double inv = 1.0 / sqrt(fabs(s2 - 2.0 * r0 * r0));
    #pragma unroll
    for (int q = 0; q < 9; ++q) {
      int c = q * 64 + l;
      if (c < D1) ws->mean[c] = (float)(r[q] * inv);
    }
  } else {
    double cc = ws->colsum[513];
    double mv[9], yv[9]; double sy = 0.0;
    #pragma unroll
    for (int q = 0; q < 9; ++q) {
      int c = q * 64 + l;
      mv[q] = 0.0; yv[q] = 0.0;
      if (c < D1) {
        double m = (double)ws->mean[c];
        double y = 0.02 * (sv[q] - cc * m) / (double)N_PTS;  // y = -R*g, R=0.01
        mv[q] = m; yv[q] = y;
        sy += y * y;
      }
    }
    #pragma unroll
    for (int m = 1; m < 64; m <<= 1) sy += __shfl_xor(sy, m);
    double y0 = __shfl(yv[0], 0);
    double n = sqrt(fabs(sy - 2.0 * y0 * y0));
    n = fmax(n, 1e-5);
    double ch = cosh(n);
    double sn = (n < 1e-4) ? (1.0 + n * n / 6.0) : (sinh(n) / n);
    double nm[9]; double s2 = 0.0;
    #pragma unroll
    for (int q = 0; q < 9; ++q) {
      int c = q * 64 + l;
      nm[q] = 0.0;
      if (c < D1) { nm[q] = ch * mv[q] + sn * yv[q]; s2 += nm[q] * nm[q]; }
    }
    #pragma unroll
    for (int m = 1; m < 64; m <<= 1) s2 += __shfl_xor(s2, m);
    double m0n = __shfl(nm[0], 0);
    double inv = 1.0 / sqrt(fabs(s2 - 2.0 * m0n * m0n));
    #pragma unroll
    for (int q = 0; q < 9; ++q) {
      int c = q * 64 + l;
      if (c < D1) ws->mean[c] = (float)(nm[q] * inv);
    }
  }
}

__global__ void write_out_kernel(const float* __restrict__ mean, float* __restrict__ out)
{
  int i = threadIdx.x;
  if (i < SDIM) out[i] = mean[1 + i];
}

extern "C" void kernel_launch(void* const* d_in, const int* in_sizes, int n_in,
                              void* d_out, int out_size, void* d_ws, size_t ws_size,
                              hipStream_t stream)
{
  (void)in_sizes; (void)n_in; (void)out_size; (void)ws_size;
  const float* data = (const float*)d_in[0];
  Ws* ws = (Ws*)d_ws;

  // init: mean = normalize(mean over N of projected). No memset needed:
  // part/colsum/mean are fully overwritten before any read each pass.
  big_kernel<true><<<dim3(GRID), dim3(BLK), 0, stream>>>(data, ws, 0);
  colreduce_kernel<<<dim3(514), dim3(64), 0, stream>>>(ws);
  finalize_kernel<true><<<dim3(1), dim3(64), 0, stream>>>(ws);

  for (int it = 0; it < NITER; ++it) {
    big_kernel<false><<<dim3(GRID), dim3(BLK), 0, stream>>>(data, ws, (it & 1) ^ 1);
    colreduce_kernel<<<dim3(514), dim3(64), 0, stream>>>(ws);
    finalize_kernel<false><<<dim3(1), dim3(64), 0, stream>>>(ws);
  }

  float* meanp = (float*)((char*)d_ws + offsetof(Ws, mean));
  write_out_kernel<<<dim3(1), dim3(512), 0, stream>>>(meanp, (float*)d_out);
}